// Round 13
// baseline (732.764 us; speedup 1.0000x reference)
//
#include <hip/hip_runtime.h>

#define NG 8   // graphs

typedef _Float16 half8  __attribute__((ext_vector_type(8)));
typedef float    f32x16 __attribute__((ext_vector_type(16)));

// ---------------- casts ----------------

__global__ __launch_bounds__(256)
void k_cast16(const float* __restrict__ in, _Float16* __restrict__ out, int n8) {
    int i = blockIdx.x * 256 + threadIdx.x;
    if (i < n8) {
        const float4 a = *(const float4*)(in + (size_t)i * 8);
        const float4 b = *(const float4*)(in + (size_t)i * 8 + 4);
        half8 o;
        o[0] = (_Float16)a.x; o[1] = (_Float16)a.y; o[2] = (_Float16)a.z; o[3] = (_Float16)a.w;
        o[4] = (_Float16)b.x; o[5] = (_Float16)b.y; o[6] = (_Float16)b.z; o[7] = (_Float16)b.w;
        *(half8*)(out + (size_t)i * 8) = o;
    }
}

// All 6 weight matrices -> fp16 in FRAGMENT-LINEAR layout:
// out elem8 index j = kslot*C + c  holds  W[c][kslot*8 .. +8]   (C = out-cols, K = depth).
// segments (elem8): w1_0 4096 | w2_0 8192 | w1_1 8192 | w2_1 8192 | w1_2 4096 | w2_2 2048
__global__ __launch_bounds__(256)
void k_castw(const float* __restrict__ w0, const float* __restrict__ w1,
             const float* __restrict__ w2, const float* __restrict__ w3,
             const float* __restrict__ w4, const float* __restrict__ w5,
             _Float16* __restrict__ o0, _Float16* __restrict__ o1,
             _Float16* __restrict__ o2, _Float16* __restrict__ o3,
             _Float16* __restrict__ o4, _Float16* __restrict__ o5) {
    int i = blockIdx.x * 256 + threadIdx.x;
    const float* in; _Float16* out; int off, lgC, K;
    if      (i <  4096) { in = w0; out = o0; off = 0;     lgC = 8; K = 128; }
    else if (i < 12288) { in = w1; out = o1; off = 4096;  lgC = 8; K = 256; }
    else if (i < 20480) { in = w2; out = o2; off = 12288; lgC = 8; K = 256; }
    else if (i < 28672) { in = w3; out = o3; off = 20480; lgC = 8; K = 256; }
    else if (i < 32768) { in = w4; out = o4; off = 28672; lgC = 7; K = 256; }
    else if (i < 34816) { in = w5; out = o5; off = 32768; lgC = 7; K = 128; }
    else return;
    int j = i - off;
    int kslot = j >> lgC;
    int c = j & ((1 << lgC) - 1);
    const float* s = in + (size_t)c * K + kslot * 8;
    const float4 a = *(const float4*)(s);
    const float4 b = *(const float4*)(s + 4);
    half8 o;
    o[0] = (_Float16)a.x; o[1] = (_Float16)a.y; o[2] = (_Float16)a.z; o[3] = (_Float16)a.w;
    o[4] = (_Float16)b.x; o[5] = (_Float16)b.y; o[6] = (_Float16)b.z; o[7] = (_Float16)b.w;
    *(half8*)(out + (size_t)j * 8) = o;
}

// ---------------- CSR build ----------------

__global__ __launch_bounds__(256)
void k_deg(const int* __restrict__ dst, int* __restrict__ deg, int E) {
    int i = blockIdx.x * 256 + threadIdx.x;
    if (i < E) atomicAdd(&deg[dst[i]], 1);
}

__global__ __launch_bounds__(1024)
void k_scan_a(const int* __restrict__ deg, int* __restrict__ incl,
              int* __restrict__ bsum, int n) {
    __shared__ int s[1024];
    int t = threadIdx.x;
    int base = blockIdx.x * 1024;
    int v = (base + t < n) ? deg[base + t] : 0;
    s[t] = v;
    __syncthreads();
    for (int off = 1; off < 1024; off <<= 1) {
        int x = 0;
        if (t >= off) x = s[t - off];
        __syncthreads();
        if (t >= off) s[t] += x;
        __syncthreads();
    }
    if (base + t < n) incl[base + t] = s[t];
    if (t == 1023) bsum[blockIdx.x] = s[1023];
}

__global__ void k_scan_b(int* bsum, int nb) {
    if (threadIdx.x == 0 && blockIdx.x == 0) {
        int run = 0;
        for (int i = 0; i < nb; ++i) { int v = bsum[i]; bsum[i] = run; run += v; }
    }
}

__global__ __launch_bounds__(256)
void k_scan_c(const int* __restrict__ incl, const int* __restrict__ deg,
              const int* __restrict__ bsum, int* __restrict__ rowp, int n) {
    int i = blockIdx.x * 256 + threadIdx.x;
    if (i < n) rowp[i] = incl[i] - deg[i] + bsum[i >> 10];
}

__global__ __launch_bounds__(256)
void k_scatter(const int* __restrict__ src, const int* __restrict__ dst,
               const int* __restrict__ rowp, int* __restrict__ cur,
               int* __restrict__ ss, int E) {
    int i = blockIdx.x * 256 + threadIdx.x;
    if (i < E) {
        int d = dst[i];
        int pos = rowp[d] + atomicAdd(&cur[d], 1);
        ss[pos] = src[i];
    }
}

// ---------------- aggregation (fp16 rows, fp32 accum), fused BN-apply+ReLU ----------------

template<int K, bool AFFINE>
__global__ __launch_bounds__(256)
void k_agg16(const _Float16* __restrict__ h, const int* __restrict__ rowp,
             const int* __restrict__ deg, const int* __restrict__ ss,
             const float* __restrict__ eps, const float* __restrict__ scp,
             const float* __restrict__ shp, _Float16* __restrict__ z, int n) {
    constexpr int TPN = K / 8;
    constexpr int NPB = 256 / TPN;
    int node = blockIdx.x * NPB + threadIdx.x / TPN;
    int lane = threadIdx.x % TPN;
    if (node >= n) return;
    float e1 = 1.0f + eps[0];
    const int c0 = lane * 8;
    float sc[8], sh[8];
    if (AFFINE) {
#pragma unroll
        for (int e = 0; e < 8; ++e) { sc[e] = scp[c0 + e]; sh[e] = shp[c0 + e]; }
    }
    size_t base = (size_t)node * K + c0;
    half8 v = *(const half8*)(h + base);
    float a[8];
#pragma unroll
    for (int e = 0; e < 8; ++e) {
        float f = (float)v[e];
        if (AFFINE) f = fmaxf(f * sc[e] + sh[e], 0.0f);
        a[e] = f * e1;
    }
    int s  = rowp[node];
    int dn = deg[node];
    int j = 0;
    for (; j + 4 <= dn; j += 4) {
        int u0 = ss[s + j], u1 = ss[s + j + 1], u2 = ss[s + j + 2], u3 = ss[s + j + 3];
        half8 h0 = *(const half8*)(h + (size_t)u0 * K + c0);
        half8 h1 = *(const half8*)(h + (size_t)u1 * K + c0);
        half8 h2 = *(const half8*)(h + (size_t)u2 * K + c0);
        half8 h3 = *(const half8*)(h + (size_t)u3 * K + c0);
#pragma unroll
        for (int e = 0; e < 8; ++e) {
            float f0 = (float)h0[e], f1 = (float)h1[e];
            float f2 = (float)h2[e], f3 = (float)h3[e];
            if (AFFINE) {
                f0 = fmaxf(f0 * sc[e] + sh[e], 0.0f);
                f1 = fmaxf(f1 * sc[e] + sh[e], 0.0f);
                f2 = fmaxf(f2 * sc[e] + sh[e], 0.0f);
                f3 = fmaxf(f3 * sc[e] + sh[e], 0.0f);
            }
            a[e] += (f0 + f1) + (f2 + f3);
        }
    }
    for (; j < dn; ++j) {
        int u = ss[s + j];
        half8 hv = *(const half8*)(h + (size_t)u * K + c0);
#pragma unroll
        for (int e = 0; e < 8; ++e) {
            float f = (float)hv[e];
            if (AFFINE) f = fmaxf(f * sc[e] + sh[e], 0.0f);
            a[e] += f;
        }
    }
    half8 o;
#pragma unroll
    for (int e = 0; e < 8; ++e) o[e] = (_Float16)a[e];
    *(half8*)(z + base) = o;
}

// ---------------- fused MLP v3b: persistent, W in regs, 64KB LDS (2 blocks/CU) ----------------
// Transpose buffer lives inside Ys (safe: barrier gamma after phase 2).
// Barriers per tile: alpha (As staged), beta (Ys written), gamma (p2 done).

template<int K, int MID, int MOUT>
__global__ __launch_bounds__(512)
void k_mlp3(const _Float16* __restrict__ A, const _Float16* __restrict__ W1,
            const float* __restrict__ b1, const _Float16* __restrict__ W2,
            const float* __restrict__ b2, _Float16* __restrict__ C,
            float* __restrict__ partial, int n, int ntiles) {
    constexpr int NK1 = K / 16;
    constexpr int NK2 = MID / 16;
    constexpr int MF1 = (MID == 256) ? 2 : 1;
    constexpr int MF2 = (MOUT == 256) ? 2 : 1;
    constexpr int NLD = K / 64;          // uint4 A-loads per thread
    __shared__ char As[64 * 512];        // swizzled: 16B slot l -> l ^ (row&31)
    __shared__ char Ys[64 * 512];        // also hosts per-wave transpose bufs post-gamma
    const int tid  = threadIdx.x;
    const int lane = tid & 63;
    const int wid  = tid >> 6;
    const int lo   = lane & 31;
    const int hi   = lane >> 5;

    const int wc1 = (MID == 256) ? wid : (wid & 3);
    const int wr1 = (MID == 256) ? 0   : (wid >> 2);
    const int colbase1 = wc1 * 32;
    const int wc2 = (MOUT == 256) ? wid : (wid & 3);
    const int wr2 = (MOUT == 256) ? 0   : (wid >> 2);
    const int colbase2 = wc2 * 32;

    // ---- W fragments + biases, once per block (frag-linear: coalesced) ----
    half8 w1f[NK1], w2f[NK2];
#pragma unroll
    for (int ks = 0; ks < NK1; ++ks)
        w1f[ks] = *(const half8*)(W1 + ((size_t)(ks * 2 + hi) * MID + colbase1 + lo) * 8);
#pragma unroll
    for (int ks = 0; ks < NK2; ++ks)
        w2f[ks] = *(const half8*)(W2 + ((size_t)(ks * 2 + hi) * MOUT + colbase2 + lo) * 8);
    const float bb1 = b1[colbase1 + lo];
    const float bb2 = b2[colbase2 + lo];

    const int sr = tid >> 3;         // staging row 0..63
    const int sl = tid & 7;          // staging 16B slot base
    const int g  = lane & 3;         // epilogue col group
    const int rl = lane >> 2;        // epilogue row lane
    char* tb = Ys + wid * 2304;      // [32][72B], valid post-gamma

    float s[8], q[8];
#pragma unroll
    for (int e = 0; e < 8; ++e) { s[e] = 0.f; q[e] = 0.f; }

    int tile = blockIdx.x;
    uint4 ar[NLD];
    if (tile < ntiles) {
        int ga = tile * 64 + sr; if (ga > n - 1) ga = n - 1;
        const char* Ab = (const char*)(A + (size_t)ga * K);
#pragma unroll
        for (int i = 0; i < NLD; ++i) ar[i] = *(const uint4*)(Ab + (sl + i * 8) * 16);
    }

    for (; tile < ntiles; tile += gridDim.x) {
        const int brow = tile * 64;

        // (1) As <- ar  (post-beta of prev iter: As readers done; tb readers done pre-alpha)
#pragma unroll
        for (int i = 0; i < NLD; ++i)
            *(uint4*)(As + sr * 512 + (((sl + i * 8) ^ (sr & 31)) << 4)) = ar[i];
        int nt = tile + gridDim.x;
        if (nt < ntiles) {
            int ga = nt * 64 + sr; if (ga > n - 1) ga = n - 1;
            const char* Ab = (const char*)(A + (size_t)ga * K);
#pragma unroll
            for (int i = 0; i < NLD; ++i) ar[i] = *(const uint4*)(Ab + (sl + i * 8) * 16);
        }
        __syncthreads();   // alpha: As ready; all waves' epilogue (tb in Ys) done

        // ---- phase 1: Y = relu(A @ W1^T + b1) ----
        f32x16 acc1[MF1];
#pragma unroll
        for (int mf = 0; mf < MF1; ++mf)
#pragma unroll
            for (int e = 0; e < 16; ++e) acc1[mf][e] = 0.0f;
#pragma unroll
        for (int ks = 0; ks < NK1; ++ks) {
#pragma unroll
            for (int mf = 0; mf < MF1; ++mf) {
                int r = ((wr1 + mf) << 5) + lo;
                half8 af = *(const half8*)(As + r * 512 + ((ks * 32 + hi * 16) ^ ((r & 31) << 4)));
                acc1[mf] = __builtin_amdgcn_mfma_f32_32x32x16_f16(af, w1f[ks], acc1[mf], 0, 0, 0);
            }
        }
#pragma unroll
        for (int mf = 0; mf < MF1; ++mf) {
            int rb = ((wr1 + mf) << 5) + (hi << 2);
#pragma unroll
            for (int j = 0; j < 16; ++j) {
                int r = rb + (j & 3) + ((j >> 2) << 3);
                float v = fmaxf(acc1[mf][j] + bb1, 0.0f);
                *(_Float16*)(Ys + r * 512 + (((colbase1 + lo) * 2) ^ ((r & 31) << 4))) = (_Float16)v;
            }
        }
        __syncthreads();   // beta: Ys ready; As fully consumed

        // ---- phase 2: C = Y @ W2^T + b2 ----
        f32x16 acc2[MF2];
#pragma unroll
        for (int mf = 0; mf < MF2; ++mf)
#pragma unroll
            for (int e = 0; e < 16; ++e) acc2[mf][e] = 0.0f;
#pragma unroll
        for (int ks = 0; ks < NK2; ++ks) {
#pragma unroll
            for (int mf = 0; mf < MF2; ++mf) {
                int r = ((wr2 + mf) << 5) + lo;
                half8 af = *(const half8*)(Ys + r * 512 + ((ks * 32 + hi * 16) ^ ((r & 31) << 4)));
                acc2[mf] = __builtin_amdgcn_mfma_f32_32x32x16_f16(af, w2f[ks], acc2[mf], 0, 0, 0);
            }
        }
        __syncthreads();   // gamma: all waves done reading Ys; tb region reusable

        // ---- epilogue: per-wave LDS transpose -> coalesced stores + BN accum ----
#pragma unroll
        for (int mf = 0; mf < MF2; ++mf) {
#pragma unroll
            for (int j = 0; j < 16; ++j) {
                int tr = (j & 3) + ((j >> 2) << 3) + (hi << 2);
                *(_Float16*)(tb + tr * 72 + lo * 2) = (_Float16)(acc2[mf][j] + bb2);
            }
            // per-wave DS ops in order: reads below see writes above
#pragma unroll
            for (int it = 0; it < 2; ++it) {
                int lr = it * 16 + rl;
                int grow = brow + ((wr2 + mf) << 5) + lr;
                half8 v = *(const half8*)(tb + lr * 72 + g * 16);
                if (grow < n) {
                    *(half8*)(C + (size_t)grow * MOUT + colbase2 + g * 8) = v;
#pragma unroll
                    for (int e = 0; e < 8; ++e) { float f = (float)v[e]; s[e] += f; q[e] += f * f; }
                }
            }
        }
    }

    // ---- BN partials: one row per (block, row-group), written once ----
#pragma unroll
    for (int e = 0; e < 8; ++e) {
        for (int mk = 4; mk < 64; mk <<= 1) {
            s[e] += __shfl_xor(s[e], mk, 64);
            q[e] += __shfl_xor(q[e], mk, 64);
        }
    }
    if (lane < 4) {
        float* p = partial + ((size_t)blockIdx.x * 2 + wr2) * (2 * MOUT);
#pragma unroll
        for (int e = 0; e < 8; ++e) {
            p[colbase2 + lane * 8 + e]        = s[e];
            p[MOUT + colbase2 + lane * 8 + e] = q[e];
        }
    }
}

// ---------------- BN reduce: strided partial rows -> scale/shift ----------------

template<int M>
__global__ __launch_bounds__(256)
void k_bnred(const float* __restrict__ partial, const float* __restrict__ gamma,
             const float* __restrict__ beta, float* __restrict__ scale,
             float* __restrict__ shift, int n, int count, int step) {
    const int w = threadIdx.x >> 6, lane = threadIdx.x & 63;
    const int c = blockIdx.x * 4 + w;
    float s = 0.f, q = 0.f;
    for (int b = lane; b < count; b += 64) {
        const float* p = partial + (size_t)(b * step) * (2 * M);
        s += p[c];
        q += p[M + c];
    }
#pragma unroll
    for (int mk = 1; mk < 64; mk <<= 1) {
        s += __shfl_xor(s, mk, 64);
        q += __shfl_xor(q, mk, 64);
    }
    if (lane == 0) {
        float invN = 1.0f / (float)n;
        float mean = s * invN;
        float var  = q * invN - mean * mean;
        float sc   = rsqrtf(var + 1e-5f) * gamma[c];
        scale[c] = sc;
        shift[c] = beta[c] - mean * sc;
    }
}

// ---------------- graph readout v2: wide parallel, per-block partials ----------------
// grid RB=1024 x 256 thr. 16 threads/row (half8), 16 rows/block-iter.
// Partials: rpart[b][NG*128], rcnt[b][NG]; reduced by k_final2.

__global__ __launch_bounds__(256)
void k_readout2(const _Float16* __restrict__ z, const float* __restrict__ scale,
                const float* __restrict__ shift, const int* __restrict__ gid,
                float* __restrict__ rpart, int* __restrict__ rcnt, int n) {
    __shared__ float ls[NG * 128];
    __shared__ int   lc[NG];
    for (int i = threadIdx.x; i < NG * 128; i += 256) ls[i] = 0.0f;
    if (threadIdx.x < NG) lc[threadIdx.x] = 0;
    __syncthreads();
    const int c16 = threadIdx.x & 15;
    const int ro  = threadIdx.x >> 4;       // 0..15
    const int c0  = c16 * 8;
    float sc[8], sh[8];
#pragma unroll
    for (int e = 0; e < 8; ++e) { sc[e] = scale[c0 + e]; sh[e] = shift[c0 + e]; }
    for (int r = blockIdx.x * 16 + ro; r < n; r += gridDim.x * 16) {
        int g = gid[r];
        half8 v = *(const half8*)(z + (size_t)r * 128 + c0);
#pragma unroll
        for (int e = 0; e < 8; ++e)
            atomicAdd(&ls[g * 128 + c0 + e], (float)v[e] * sc[e] + sh[e]);
        if (c16 == 0) atomicAdd(&lc[g], 1);
    }
    __syncthreads();
    float* p = rpart + (size_t)blockIdx.x * (NG * 128);
    for (int i = threadIdx.x; i < NG * 128; i += 256) p[i] = ls[i];
    if (threadIdx.x < NG) rcnt[blockIdx.x * NG + threadIdx.x] = lc[threadIdx.x];
}

__global__ __launch_bounds__(256)
void k_final2(const float* __restrict__ rpart, const int* __restrict__ rcnt,
              float* __restrict__ out, int nbr) {
    int i = blockIdx.x * 256 + threadIdx.x;
    if (i >= NG * 128) return;
    int g = i >> 7;
    float s = 0.0f;
    for (int b = 0; b < nbr; ++b) s += rpart[(size_t)b * (NG * 128) + i];
    int cnt = 0;
    for (int b = 0; b < nbr; ++b) cnt += rcnt[b * NG + g];
    out[i] = s / fmaxf((float)cnt, 1.0f);
}

// ---------------- host ----------------

extern "C" void kernel_launch(void* const* d_in, const int* in_sizes, int n_in,
                              void* d_out, int out_size, void* d_ws, size_t ws_size,
                              hipStream_t stream) {
    const float* x   = (const float*)d_in[0];
    const int*   src = (const int*)d_in[1];
    const int*   dst = (const int*)d_in[2];
    const int*   gid = (const int*)d_in[3];
    const int n = in_sizes[0] / 128;
    const int E = in_sizes[1];

    auto align = [](size_t o) { return (o + 255) & ~(size_t)255; };
    char* ws = (char*)d_ws;
    size_t off = 0;
    const size_t SZ_H = align((size_t)n * 256 * sizeof(_Float16));
    const size_t SZ_I = align((size_t)n * sizeof(int));
    const int gx = (n + 63) / 64;
    const int NBLK = 512;   // 2 blocks/CU (64KB LDS each)
    const int RB   = 1024;  // readout blocks

    _Float16* h0 = (_Float16*)(ws + off); off += align((size_t)n * 128 * sizeof(_Float16));
    _Float16* P0 = (_Float16*)(ws + off); off += SZ_H;
    _Float16* P1 = (_Float16*)(ws + off); off += SZ_H;
    int*   deg  = (int*)(ws + off);   off += SZ_I;
    int*   incl = (int*)(ws + off);   off += SZ_I;
    int*   rowp = (int*)(ws + off);   off += SZ_I;
    int*   cur  = (int*)(ws + off);   off += SZ_I;
    int*   bsum = (int*)(ws + off);   off += 256 * sizeof(int);
    int*   ss   = (int*)(ws + off);   off += align((size_t)E * sizeof(int));
    float* partial = (float*)(ws + off); off += align((size_t)(2 * NBLK) * 2 * 256 * sizeof(float));
    float* scale   = (float*)(ws + off); off += align(256 * sizeof(float));
    float* shiftb  = (float*)(ws + off); off += align(256 * sizeof(float));
    float* rpart = (float*)(ws + off); off += align((size_t)RB * NG * 128 * sizeof(float));
    int*   rcnt  = (int*)(ws + off);  off += align((size_t)RB * NG * sizeof(int));
    _Float16* wh[6];
    for (int i = 0; i < 6; ++i) { wh[i] = (_Float16*)(ws + off); off += align(65536 * sizeof(_Float16)); }

    // ---- casts ----
    k_cast16<<<(n * 128 / 8 + 255) / 256, 256, 0, stream>>>(x, h0, n * 128 / 8);
    k_castw<<<136, 256, 0, stream>>>(
        (const float*)d_in[4], (const float*)d_in[6],
        (const float*)d_in[11], (const float*)d_in[13],
        (const float*)d_in[18], (const float*)d_in[20],
        wh[0], wh[1], wh[2], wh[3], wh[4], wh[5]);

    // ---- CSR build (dst-keyed) ----
    hipMemsetAsync(deg, 0, (size_t)n * sizeof(int), stream);
    k_deg<<<(E + 255) / 256, 256, 0, stream>>>(dst, deg, E);
    int nb = (n + 1023) / 1024;
    k_scan_a<<<nb, 1024, 0, stream>>>(deg, incl, bsum, n);
    k_scan_b<<<1, 1, 0, stream>>>(bsum, nb);
    k_scan_c<<<(n + 255) / 256, 256, 0, stream>>>(incl, deg, bsum, rowp, n);
    hipMemsetAsync(cur, 0, (size_t)n * sizeof(int), stream);
    k_scatter<<<(E + 255) / 256, 256, 0, stream>>>(src, dst, rowp, cur, ss, E);

    // ---- layers ----
    for (int L = 0; L < 3; ++L) {
        const int base = 4 + 7 * L;
        const float* b1    = (const float*)d_in[base + 1];
        const float* b2    = (const float*)d_in[base + 3];
        const float* eps   = (const float*)d_in[base + 4];
        const float* gamma = (const float*)d_in[base + 5];
        const float* beta  = (const float*)d_in[base + 6];

        if (L == 0) {
            k_agg16<128, false><<<(n + 15) / 16, 256, 0, stream>>>(
                h0, rowp, deg, ss, eps, nullptr, nullptr, P1, n);
            k_mlp3<128, 256, 256><<<NBLK, 512, 0, stream>>>(P1, wh[0], b1, wh[1], b2, P0, partial, n, gx);
            k_bnred<256><<<64, 256, 0, stream>>>(partial, gamma, beta, scale, shiftb, n, NBLK, 2);
        } else if (L == 1) {
            k_agg16<256, true><<<(n + 7) / 8, 256, 0, stream>>>(
                P0, rowp, deg, ss, eps, scale, shiftb, P1, n);
            k_mlp3<256, 256, 256><<<NBLK, 512, 0, stream>>>(P1, wh[2], b1, wh[3], b2, P0, partial, n, gx);
            k_bnred<256><<<64, 256, 0, stream>>>(partial, gamma, beta, scale, shiftb, n, NBLK, 2);
        } else {
            k_agg16<256, true><<<(n + 7) / 8, 256, 0, stream>>>(
                P0, rowp, deg, ss, eps, scale, shiftb, P1, n);
            k_mlp3<256, 128, 128><<<NBLK, 512, 0, stream>>>(P1, wh[4], b1, wh[5], b2, P0, partial, n, gx);
            k_bnred<128><<<32, 256, 0, stream>>>(partial, gamma, beta, scale, shiftb, n, 2 * NBLK, 1);
        }
    }

    // ---- readout (applies layer-2 BN affine) ----
    k_readout2<<<RB, 256, 0, stream>>>(P0, scale, shiftb, gid, rpart, rcnt, n);
    k_final2<<<4, 256, 0, stream>>>(rpart, rcnt, (float*)d_out, RB);
}

// Round 14
// 416.329 us; speedup vs baseline: 1.7601x; 1.7601x over previous
//
#include <hip/hip_runtime.h>

#define NG 8   // graphs

typedef _Float16 half8  __attribute__((ext_vector_type(8)));
typedef float    f32x16 __attribute__((ext_vector_type(16)));

// ---------------- casts ----------------

__global__ __launch_bounds__(256)
void k_cast16(const float* __restrict__ in, _Float16* __restrict__ out, int n8) {
    int i = blockIdx.x * 256 + threadIdx.x;
    if (i < n8) {
        const float4 a = *(const float4*)(in + (size_t)i * 8);
        const float4 b = *(const float4*)(in + (size_t)i * 8 + 4);
        half8 o;
        o[0] = (_Float16)a.x; o[1] = (_Float16)a.y; o[2] = (_Float16)a.z; o[3] = (_Float16)a.w;
        o[4] = (_Float16)b.x; o[5] = (_Float16)b.y; o[6] = (_Float16)b.z; o[7] = (_Float16)b.w;
        *(half8*)(out + (size_t)i * 8) = o;
    }
}

// All 6 weight matrices -> fp16 in FRAGMENT-LINEAR layout:
// out elem8 index j = kslot*C + c  holds  W[c][kslot*8 .. +8]   (C = out-cols, K = depth).
// segments (elem8): w1_0 4096 | w2_0 8192 | w1_1 8192 | w2_1 8192 | w1_2 4096 | w2_2 2048
__global__ __launch_bounds__(256)
void k_castw(const float* __restrict__ w0, const float* __restrict__ w1,
             const float* __restrict__ w2, const float* __restrict__ w3,
             const float* __restrict__ w4, const float* __restrict__ w5,
             _Float16* __restrict__ o0, _Float16* __restrict__ o1,
             _Float16* __restrict__ o2, _Float16* __restrict__ o3,
             _Float16* __restrict__ o4, _Float16* __restrict__ o5) {
    int i = blockIdx.x * 256 + threadIdx.x;
    const float* in; _Float16* out; int off, lgC, K;
    if      (i <  4096) { in = w0; out = o0; off = 0;     lgC = 8; K = 128; }
    else if (i < 12288) { in = w1; out = o1; off = 4096;  lgC = 8; K = 256; }
    else if (i < 20480) { in = w2; out = o2; off = 12288; lgC = 8; K = 256; }
    else if (i < 28672) { in = w3; out = o3; off = 20480; lgC = 8; K = 256; }
    else if (i < 32768) { in = w4; out = o4; off = 28672; lgC = 7; K = 256; }
    else if (i < 34816) { in = w5; out = o5; off = 32768; lgC = 7; K = 128; }
    else return;
    int j = i - off;
    int kslot = j >> lgC;
    int c = j & ((1 << lgC) - 1);
    const float* s = in + (size_t)c * K + kslot * 8;
    const float4 a = *(const float4*)(s);
    const float4 b = *(const float4*)(s + 4);
    half8 o;
    o[0] = (_Float16)a.x; o[1] = (_Float16)a.y; o[2] = (_Float16)a.z; o[3] = (_Float16)a.w;
    o[4] = (_Float16)b.x; o[5] = (_Float16)b.y; o[6] = (_Float16)b.z; o[7] = (_Float16)b.w;
    *(half8*)(out + (size_t)j * 8) = o;
}

// ---------------- CSR build ----------------

__global__ __launch_bounds__(256)
void k_deg(const int* __restrict__ dst, int* __restrict__ deg, int E) {
    int i = blockIdx.x * 256 + threadIdx.x;
    if (i < E) atomicAdd(&deg[dst[i]], 1);
}

__global__ __launch_bounds__(1024)
void k_scan_a(const int* __restrict__ deg, int* __restrict__ incl,
              int* __restrict__ bsum, int n) {
    __shared__ int s[1024];
    int t = threadIdx.x;
    int base = blockIdx.x * 1024;
    int v = (base + t < n) ? deg[base + t] : 0;
    s[t] = v;
    __syncthreads();
    for (int off = 1; off < 1024; off <<= 1) {
        int x = 0;
        if (t >= off) x = s[t - off];
        __syncthreads();
        if (t >= off) s[t] += x;
        __syncthreads();
    }
    if (base + t < n) incl[base + t] = s[t];
    if (t == 1023) bsum[blockIdx.x] = s[1023];
}

__global__ void k_scan_b(int* bsum, int nb) {
    if (threadIdx.x == 0 && blockIdx.x == 0) {
        int run = 0;
        for (int i = 0; i < nb; ++i) { int v = bsum[i]; bsum[i] = run; run += v; }
    }
}

__global__ __launch_bounds__(256)
void k_scan_c(const int* __restrict__ incl, const int* __restrict__ deg,
              const int* __restrict__ bsum, int* __restrict__ rowp, int n) {
    int i = blockIdx.x * 256 + threadIdx.x;
    if (i < n) rowp[i] = incl[i] - deg[i] + bsum[i >> 10];
}

__global__ __launch_bounds__(256)
void k_scatter(const int* __restrict__ src, const int* __restrict__ dst,
               const int* __restrict__ rowp, int* __restrict__ cur,
               int* __restrict__ ss, int E) {
    int i = blockIdx.x * 256 + threadIdx.x;
    if (i < E) {
        int d = dst[i];
        int pos = rowp[d] + atomicAdd(&cur[d], 1);
        ss[pos] = src[i];
    }
}

// ---------------- aggregation (fp16 rows, fp32 accum), fused BN-apply+ReLU ----------------

template<int K, bool AFFINE>
__global__ __launch_bounds__(256)
void k_agg16(const _Float16* __restrict__ h, const int* __restrict__ rowp,
             const int* __restrict__ deg, const int* __restrict__ ss,
             const float* __restrict__ eps, const float* __restrict__ scp,
             const float* __restrict__ shp, _Float16* __restrict__ z, int n) {
    constexpr int TPN = K / 8;
    constexpr int NPB = 256 / TPN;
    int node = blockIdx.x * NPB + threadIdx.x / TPN;
    int lane = threadIdx.x % TPN;
    if (node >= n) return;
    float e1 = 1.0f + eps[0];
    const int c0 = lane * 8;
    float sc[8], sh[8];
    if (AFFINE) {
#pragma unroll
        for (int e = 0; e < 8; ++e) { sc[e] = scp[c0 + e]; sh[e] = shp[c0 + e]; }
    }
    size_t base = (size_t)node * K + c0;
    half8 v = *(const half8*)(h + base);
    float a[8];
#pragma unroll
    for (int e = 0; e < 8; ++e) {
        float f = (float)v[e];
        if (AFFINE) f = fmaxf(f * sc[e] + sh[e], 0.0f);
        a[e] = f * e1;
    }
    int s  = rowp[node];
    int dn = deg[node];
    int j = 0;
    for (; j + 4 <= dn; j += 4) {
        int u0 = ss[s + j], u1 = ss[s + j + 1], u2 = ss[s + j + 2], u3 = ss[s + j + 3];
        half8 h0 = *(const half8*)(h + (size_t)u0 * K + c0);
        half8 h1 = *(const half8*)(h + (size_t)u1 * K + c0);
        half8 h2 = *(const half8*)(h + (size_t)u2 * K + c0);
        half8 h3 = *(const half8*)(h + (size_t)u3 * K + c0);
#pragma unroll
        for (int e = 0; e < 8; ++e) {
            float f0 = (float)h0[e], f1 = (float)h1[e];
            float f2 = (float)h2[e], f3 = (float)h3[e];
            if (AFFINE) {
                f0 = fmaxf(f0 * sc[e] + sh[e], 0.0f);
                f1 = fmaxf(f1 * sc[e] + sh[e], 0.0f);
                f2 = fmaxf(f2 * sc[e] + sh[e], 0.0f);
                f3 = fmaxf(f3 * sc[e] + sh[e], 0.0f);
            }
            a[e] += (f0 + f1) + (f2 + f3);
        }
    }
    for (; j < dn; ++j) {
        int u = ss[s + j];
        half8 hv = *(const half8*)(h + (size_t)u * K + c0);
#pragma unroll
        for (int e = 0; e < 8; ++e) {
            float f = (float)hv[e];
            if (AFFINE) f = fmaxf(f * sc[e] + sh[e], 0.0f);
            a[e] += f;
        }
    }
    half8 o;
#pragma unroll
    for (int e = 0; e < 8; ++e) o[e] = (_Float16)a[e];
    *(half8*)(z + base) = o;
}

// ---------------- fused MLP v3b: persistent, W in regs, 64KB LDS (2 blocks/CU) ----------------
// Transpose buffer lives inside Ys (safe: barrier gamma after phase 2).
// Barriers per tile: alpha (As staged), beta (Ys written), gamma (p2 done).

template<int K, int MID, int MOUT>
__global__ __launch_bounds__(512)
void k_mlp3(const _Float16* __restrict__ A, const _Float16* __restrict__ W1,
            const float* __restrict__ b1, const _Float16* __restrict__ W2,
            const float* __restrict__ b2, _Float16* __restrict__ C,
            float* __restrict__ partial, int n, int ntiles) {
    constexpr int NK1 = K / 16;
    constexpr int NK2 = MID / 16;
    constexpr int MF1 = (MID == 256) ? 2 : 1;
    constexpr int MF2 = (MOUT == 256) ? 2 : 1;
    constexpr int NLD = K / 64;          // uint4 A-loads per thread
    __shared__ char As[64 * 512];        // swizzled: 16B slot l -> l ^ (row&31)
    __shared__ char Ys[64 * 512];        // also hosts per-wave transpose bufs post-gamma
    const int tid  = threadIdx.x;
    const int lane = tid & 63;
    const int wid  = tid >> 6;
    const int lo   = lane & 31;
    const int hi   = lane >> 5;

    const int wc1 = (MID == 256) ? wid : (wid & 3);
    const int wr1 = (MID == 256) ? 0   : (wid >> 2);
    const int colbase1 = wc1 * 32;
    const int wc2 = (MOUT == 256) ? wid : (wid & 3);
    const int wr2 = (MOUT == 256) ? 0   : (wid >> 2);
    const int colbase2 = wc2 * 32;

    // ---- W fragments + biases, once per block (frag-linear: coalesced) ----
    half8 w1f[NK1], w2f[NK2];
#pragma unroll
    for (int ks = 0; ks < NK1; ++ks)
        w1f[ks] = *(const half8*)(W1 + ((size_t)(ks * 2 + hi) * MID + colbase1 + lo) * 8);
#pragma unroll
    for (int ks = 0; ks < NK2; ++ks)
        w2f[ks] = *(const half8*)(W2 + ((size_t)(ks * 2 + hi) * MOUT + colbase2 + lo) * 8);
    const float bb1 = b1[colbase1 + lo];
    const float bb2 = b2[colbase2 + lo];

    const int sr = tid >> 3;         // staging row 0..63
    const int sl = tid & 7;          // staging 16B slot base
    const int g  = lane & 3;         // epilogue col group
    const int rl = lane >> 2;        // epilogue row lane
    char* tb = Ys + wid * 2304;      // [32][72B], valid post-gamma

    float s[8], q[8];
#pragma unroll
    for (int e = 0; e < 8; ++e) { s[e] = 0.f; q[e] = 0.f; }

    int tile = blockIdx.x;
    uint4 ar[NLD];
    if (tile < ntiles) {
        int ga = tile * 64 + sr; if (ga > n - 1) ga = n - 1;
        const char* Ab = (const char*)(A + (size_t)ga * K);
#pragma unroll
        for (int i = 0; i < NLD; ++i) ar[i] = *(const uint4*)(Ab + (sl + i * 8) * 16);
    }

    for (; tile < ntiles; tile += gridDim.x) {
        const int brow = tile * 64;

        // (1) As <- ar  (post-beta of prev iter: As readers done; tb readers done pre-alpha)
#pragma unroll
        for (int i = 0; i < NLD; ++i)
            *(uint4*)(As + sr * 512 + (((sl + i * 8) ^ (sr & 31)) << 4)) = ar[i];
        int nt = tile + gridDim.x;
        if (nt < ntiles) {
            int ga = nt * 64 + sr; if (ga > n - 1) ga = n - 1;
            const char* Ab = (const char*)(A + (size_t)ga * K);
#pragma unroll
            for (int i = 0; i < NLD; ++i) ar[i] = *(const uint4*)(Ab + (sl + i * 8) * 16);
        }
        __syncthreads();   // alpha: As ready; all waves' epilogue (tb in Ys) done

        // ---- phase 1: Y = relu(A @ W1^T + b1) ----
        f32x16 acc1[MF1];
#pragma unroll
        for (int mf = 0; mf < MF1; ++mf)
#pragma unroll
            for (int e = 0; e < 16; ++e) acc1[mf][e] = 0.0f;
#pragma unroll
        for (int ks = 0; ks < NK1; ++ks) {
#pragma unroll
            for (int mf = 0; mf < MF1; ++mf) {
                int r = ((wr1 + mf) << 5) + lo;
                half8 af = *(const half8*)(As + r * 512 + ((ks * 32 + hi * 16) ^ ((r & 31) << 4)));
                acc1[mf] = __builtin_amdgcn_mfma_f32_32x32x16_f16(af, w1f[ks], acc1[mf], 0, 0, 0);
            }
        }
#pragma unroll
        for (int mf = 0; mf < MF1; ++mf) {
            int rb = ((wr1 + mf) << 5) + (hi << 2);
#pragma unroll
            for (int j = 0; j < 16; ++j) {
                int r = rb + (j & 3) + ((j >> 2) << 3);
                float v = fmaxf(acc1[mf][j] + bb1, 0.0f);
                *(_Float16*)(Ys + r * 512 + (((colbase1 + lo) * 2) ^ ((r & 31) << 4))) = (_Float16)v;
            }
        }
        __syncthreads();   // beta: Ys ready; As fully consumed

        // ---- phase 2: C = Y @ W2^T + b2 ----
        f32x16 acc2[MF2];
#pragma unroll
        for (int mf = 0; mf < MF2; ++mf)
#pragma unroll
            for (int e = 0; e < 16; ++e) acc2[mf][e] = 0.0f;
#pragma unroll
        for (int ks = 0; ks < NK2; ++ks) {
#pragma unroll
            for (int mf = 0; mf < MF2; ++mf) {
                int r = ((wr2 + mf) << 5) + lo;
                half8 af = *(const half8*)(Ys + r * 512 + ((ks * 32 + hi * 16) ^ ((r & 31) << 4)));
                acc2[mf] = __builtin_amdgcn_mfma_f32_32x32x16_f16(af, w2f[ks], acc2[mf], 0, 0, 0);
            }
        }
        __syncthreads();   // gamma: all waves done reading Ys; tb region reusable

        // ---- epilogue: per-wave LDS transpose -> coalesced stores + BN accum ----
#pragma unroll
        for (int mf = 0; mf < MF2; ++mf) {
#pragma unroll
            for (int j = 0; j < 16; ++j) {
                int tr = (j & 3) + ((j >> 2) << 3) + (hi << 2);
                *(_Float16*)(tb + tr * 72 + lo * 2) = (_Float16)(acc2[mf][j] + bb2);
            }
            // per-wave DS ops in order: reads below see writes above
#pragma unroll
            for (int it = 0; it < 2; ++it) {
                int lr = it * 16 + rl;
                int grow = brow + ((wr2 + mf) << 5) + lr;
                half8 v = *(const half8*)(tb + lr * 72 + g * 16);
                if (grow < n) {
                    *(half8*)(C + (size_t)grow * MOUT + colbase2 + g * 8) = v;
#pragma unroll
                    for (int e = 0; e < 8; ++e) { float f = (float)v[e]; s[e] += f; q[e] += f * f; }
                }
            }
        }
    }

    // ---- BN partials: one row per (block, row-group), written once ----
#pragma unroll
    for (int e = 0; e < 8; ++e) {
        for (int mk = 4; mk < 64; mk <<= 1) {
            s[e] += __shfl_xor(s[e], mk, 64);
            q[e] += __shfl_xor(q[e], mk, 64);
        }
    }
    if (lane < 4) {
        float* p = partial + ((size_t)blockIdx.x * 2 + wr2) * (2 * MOUT);
#pragma unroll
        for (int e = 0; e < 8; ++e) {
            p[colbase2 + lane * 8 + e]        = s[e];
            p[MOUT + colbase2 + lane * 8 + e] = q[e];
        }
    }
}

// ---------------- BN reduce: strided partial rows -> scale/shift ----------------

template<int M>
__global__ __launch_bounds__(256)
void k_bnred(const float* __restrict__ partial, const float* __restrict__ gamma,
             const float* __restrict__ beta, float* __restrict__ scale,
             float* __restrict__ shift, int n, int count, int step) {
    const int w = threadIdx.x >> 6, lane = threadIdx.x & 63;
    const int c = blockIdx.x * 4 + w;
    float s = 0.f, q = 0.f;
    for (int b = lane; b < count; b += 64) {
        const float* p = partial + (size_t)(b * step) * (2 * M);
        s += p[c];
        q += p[M + c];
    }
#pragma unroll
    for (int mk = 1; mk < 64; mk <<= 1) {
        s += __shfl_xor(s, mk, 64);
        q += __shfl_xor(q, mk, 64);
    }
    if (lane == 0) {
        float invN = 1.0f / (float)n;
        float mean = s * invN;
        float var  = q * invN - mean * mean;
        float sc   = rsqrtf(var + 1e-5f) * gamma[c];
        scale[c] = sc;
        shift[c] = beta[c] - mean * sc;
    }
}

// ---------------- graph readout v2: wide parallel, per-block partials ----------------
// grid RB=1024 x 256 thr. 16 threads/row (half8), 16 rows/block-iter.
// Partials: rpart[b][NG*128], rcnt[b][NG]; reduced by k_final3.

__global__ __launch_bounds__(256)
void k_readout2(const _Float16* __restrict__ z, const float* __restrict__ scale,
                const float* __restrict__ shift, const int* __restrict__ gid,
                float* __restrict__ rpart, int* __restrict__ rcnt, int n) {
    __shared__ float ls[NG * 128];
    __shared__ int   lc[NG];
    for (int i = threadIdx.x; i < NG * 128; i += 256) ls[i] = 0.0f;
    if (threadIdx.x < NG) lc[threadIdx.x] = 0;
    __syncthreads();
    const int c16 = threadIdx.x & 15;
    const int ro  = threadIdx.x >> 4;       // 0..15
    const int c0  = c16 * 8;
    float sc[8], sh[8];
#pragma unroll
    for (int e = 0; e < 8; ++e) { sc[e] = scale[c0 + e]; sh[e] = shift[c0 + e]; }
    for (int r = blockIdx.x * 16 + ro; r < n; r += gridDim.x * 16) {
        int g = gid[r];
        half8 v = *(const half8*)(z + (size_t)r * 128 + c0);
#pragma unroll
        for (int e = 0; e < 8; ++e)
            atomicAdd(&ls[g * 128 + c0 + e], (float)v[e] * sc[e] + sh[e]);
        if (c16 == 0) atomicAdd(&lc[g], 1);
    }
    __syncthreads();
    float* p = rpart + (size_t)blockIdx.x * (NG * 128);
    for (int i = threadIdx.x; i < NG * 128; i += 256) p[i] = ls[i];
    if (threadIdx.x < NG) rcnt[blockIdx.x * NG + threadIdx.x] = lc[threadIdx.x];
}

// ---------------- final: one wave per output column ----------------
// grid = 256 blocks x 256 thr = 1024 waves; lanes stride partial rows.

__global__ __launch_bounds__(256)
void k_final3(const float* __restrict__ rpart, const int* __restrict__ rcnt,
              float* __restrict__ out, int nbr) {
    const int w = threadIdx.x >> 6, lane = threadIdx.x & 63;
    const int i = blockIdx.x * 4 + w;        // column 0..1023
    const int g = i >> 7;
    float s = 0.0f;
    int cnt = 0;
    for (int b = lane; b < nbr; b += 64) {
        s   += rpart[(size_t)b * (NG * 128) + i];
        cnt += rcnt[b * NG + g];
    }
#pragma unroll
    for (int mk = 1; mk < 64; mk <<= 1) {
        s   += __shfl_xor(s, mk, 64);
        cnt += __shfl_xor(cnt, mk, 64);
    }
    if (lane == 0) out[i] = s / fmaxf((float)cnt, 1.0f);
}

// ---------------- host ----------------

extern "C" void kernel_launch(void* const* d_in, const int* in_sizes, int n_in,
                              void* d_out, int out_size, void* d_ws, size_t ws_size,
                              hipStream_t stream) {
    const float* x   = (const float*)d_in[0];
    const int*   src = (const int*)d_in[1];
    const int*   dst = (const int*)d_in[2];
    const int*   gid = (const int*)d_in[3];
    const int n = in_sizes[0] / 128;
    const int E = in_sizes[1];

    auto align = [](size_t o) { return (o + 255) & ~(size_t)255; };
    char* ws = (char*)d_ws;
    size_t off = 0;
    const size_t SZ_H = align((size_t)n * 256 * sizeof(_Float16));
    const size_t SZ_I = align((size_t)n * sizeof(int));
    const int gx = (n + 63) / 64;
    const int NBLK = 512;   // 2 blocks/CU (64KB LDS each)
    const int RB   = 1024;  // readout blocks

    _Float16* h0 = (_Float16*)(ws + off); off += align((size_t)n * 128 * sizeof(_Float16));
    _Float16* P0 = (_Float16*)(ws + off); off += SZ_H;
    _Float16* P1 = (_Float16*)(ws + off); off += SZ_H;
    int*   deg  = (int*)(ws + off);   off += SZ_I;
    int*   incl = (int*)(ws + off);   off += SZ_I;
    int*   rowp = (int*)(ws + off);   off += SZ_I;
    int*   cur  = (int*)(ws + off);   off += SZ_I;
    int*   bsum = (int*)(ws + off);   off += 256 * sizeof(int);
    int*   ss   = (int*)(ws + off);   off += align((size_t)E * sizeof(int));
    float* partial = (float*)(ws + off); off += align((size_t)(2 * NBLK) * 2 * 256 * sizeof(float));
    float* scale   = (float*)(ws + off); off += align(256 * sizeof(float));
    float* shiftb  = (float*)(ws + off); off += align(256 * sizeof(float));
    float* rpart = (float*)(ws + off); off += align((size_t)RB * NG * 128 * sizeof(float));
    int*   rcnt  = (int*)(ws + off);  off += align((size_t)RB * NG * sizeof(int));
    _Float16* wh[6];
    for (int i = 0; i < 6; ++i) { wh[i] = (_Float16*)(ws + off); off += align(65536 * sizeof(_Float16)); }

    // ---- casts ----
    k_cast16<<<(n * 128 / 8 + 255) / 256, 256, 0, stream>>>(x, h0, n * 128 / 8);
    k_castw<<<136, 256, 0, stream>>>(
        (const float*)d_in[4], (const float*)d_in[6],
        (const float*)d_in[11], (const float*)d_in[13],
        (const float*)d_in[18], (const float*)d_in[20],
        wh[0], wh[1], wh[2], wh[3], wh[4], wh[5]);

    // ---- CSR build (dst-keyed) ----
    hipMemsetAsync(deg, 0, (size_t)n * sizeof(int), stream);
    k_deg<<<(E + 255) / 256, 256, 0, stream>>>(dst, deg, E);
    int nb = (n + 1023) / 1024;
    k_scan_a<<<nb, 1024, 0, stream>>>(deg, incl, bsum, n);
    k_scan_b<<<1, 1, 0, stream>>>(bsum, nb);
    k_scan_c<<<(n + 255) / 256, 256, 0, stream>>>(incl, deg, bsum, rowp, n);
    hipMemsetAsync(cur, 0, (size_t)n * sizeof(int), stream);
    k_scatter<<<(E + 255) / 256, 256, 0, stream>>>(src, dst, rowp, cur, ss, E);

    // ---- layers ----
    for (int L = 0; L < 3; ++L) {
        const int base = 4 + 7 * L;
        const float* b1    = (const float*)d_in[base + 1];
        const float* b2    = (const float*)d_in[base + 3];
        const float* eps   = (const float*)d_in[base + 4];
        const float* gamma = (const float*)d_in[base + 5];
        const float* beta  = (const float*)d_in[base + 6];

        if (L == 0) {
            k_agg16<128, false><<<(n + 15) / 16, 256, 0, stream>>>(
                h0, rowp, deg, ss, eps, nullptr, nullptr, P1, n);
            k_mlp3<128, 256, 256><<<NBLK, 512, 0, stream>>>(P1, wh[0], b1, wh[1], b2, P0, partial, n, gx);
            k_bnred<256><<<64, 256, 0, stream>>>(partial, gamma, beta, scale, shiftb, n, NBLK, 2);
        } else if (L == 1) {
            k_agg16<256, true><<<(n + 7) / 8, 256, 0, stream>>>(
                P0, rowp, deg, ss, eps, scale, shiftb, P1, n);
            k_mlp3<256, 256, 256><<<NBLK, 512, 0, stream>>>(P1, wh[2], b1, wh[3], b2, P0, partial, n, gx);
            k_bnred<256><<<64, 256, 0, stream>>>(partial, gamma, beta, scale, shiftb, n, NBLK, 2);
        } else {
            k_agg16<256, true><<<(n + 7) / 8, 256, 0, stream>>>(
                P0, rowp, deg, ss, eps, scale, shiftb, P1, n);
            k_mlp3<256, 128, 128><<<NBLK, 512, 0, stream>>>(P1, wh[4], b1, wh[5], b2, P0, partial, n, gx);
            k_bnred<128><<<32, 256, 0, stream>>>(partial, gamma, beta, scale, shiftb, n, 2 * NBLK, 1);
        }
    }

    // ---- readout (applies layer-2 BN affine) ----
    k_readout2<<<RB, 256, 0, stream>>>(P0, scale, shiftb, gid, rpart, rcnt, n);
    k_final3<<<256, 256, 0, stream>>>(rpart, rcnt, (float*)d_out, RB);
}

// Round 15
// 401.190 us; speedup vs baseline: 1.8265x; 1.0377x over previous
//
#include <hip/hip_runtime.h>

#define NG 8   // graphs

typedef _Float16 half8  __attribute__((ext_vector_type(8)));
typedef float    f32x16 __attribute__((ext_vector_type(16)));

// ---------------- casts ----------------

__global__ __launch_bounds__(256)
void k_cast16(const float* __restrict__ in, _Float16* __restrict__ out, int n8) {
    int i = blockIdx.x * 256 + threadIdx.x;
    if (i < n8) {
        const float4 a = *(const float4*)(in + (size_t)i * 8);
        const float4 b = *(const float4*)(in + (size_t)i * 8 + 4);
        half8 o;
        o[0] = (_Float16)a.x; o[1] = (_Float16)a.y; o[2] = (_Float16)a.z; o[3] = (_Float16)a.w;
        o[4] = (_Float16)b.x; o[5] = (_Float16)b.y; o[6] = (_Float16)b.z; o[7] = (_Float16)b.w;
        *(half8*)(out + (size_t)i * 8) = o;
    }
}

// All 6 weight matrices -> fp16 in FRAGMENT-LINEAR layout:
// out elem8 index j = kslot*C + c  holds  W[c][kslot*8 .. +8]   (C = out-cols, K = depth).
// segments (elem8): w1_0 4096 | w2_0 8192 | w1_1 8192 | w2_1 8192 | w1_2 4096 | w2_2 2048
__global__ __launch_bounds__(256)
void k_castw(const float* __restrict__ w0, const float* __restrict__ w1,
             const float* __restrict__ w2, const float* __restrict__ w3,
             const float* __restrict__ w4, const float* __restrict__ w5,
             _Float16* __restrict__ o0, _Float16* __restrict__ o1,
             _Float16* __restrict__ o2, _Float16* __restrict__ o3,
             _Float16* __restrict__ o4, _Float16* __restrict__ o5) {
    int i = blockIdx.x * 256 + threadIdx.x;
    const float* in; _Float16* out; int off, lgC, K;
    if      (i <  4096) { in = w0; out = o0; off = 0;     lgC = 8; K = 128; }
    else if (i < 12288) { in = w1; out = o1; off = 4096;  lgC = 8; K = 256; }
    else if (i < 20480) { in = w2; out = o2; off = 12288; lgC = 8; K = 256; }
    else if (i < 28672) { in = w3; out = o3; off = 20480; lgC = 8; K = 256; }
    else if (i < 32768) { in = w4; out = o4; off = 28672; lgC = 7; K = 256; }
    else if (i < 34816) { in = w5; out = o5; off = 32768; lgC = 7; K = 128; }
    else return;
    int j = i - off;
    int kslot = j >> lgC;
    int c = j & ((1 << lgC) - 1);
    const float* s = in + (size_t)c * K + kslot * 8;
    const float4 a = *(const float4*)(s);
    const float4 b = *(const float4*)(s + 4);
    half8 o;
    o[0] = (_Float16)a.x; o[1] = (_Float16)a.y; o[2] = (_Float16)a.z; o[3] = (_Float16)a.w;
    o[4] = (_Float16)b.x; o[5] = (_Float16)b.y; o[6] = (_Float16)b.z; o[7] = (_Float16)b.w;
    *(half8*)(out + (size_t)j * 8) = o;
}

// ---------------- CSR build ----------------

__global__ __launch_bounds__(256)
void k_deg(const int* __restrict__ dst, int* __restrict__ deg, int E) {
    int i = blockIdx.x * 256 + threadIdx.x;
    if (i < E) atomicAdd(&deg[dst[i]], 1);
}

__global__ __launch_bounds__(1024)
void k_scan_a(const int* __restrict__ deg, int* __restrict__ incl,
              int* __restrict__ bsum, int n) {
    __shared__ int s[1024];
    int t = threadIdx.x;
    int base = blockIdx.x * 1024;
    int v = (base + t < n) ? deg[base + t] : 0;
    s[t] = v;
    __syncthreads();
    for (int off = 1; off < 1024; off <<= 1) {
        int x = 0;
        if (t >= off) x = s[t - off];
        __syncthreads();
        if (t >= off) s[t] += x;
        __syncthreads();
    }
    if (base + t < n) incl[base + t] = s[t];
    if (t == 1023) bsum[blockIdx.x] = s[1023];
}

__global__ void k_scan_b(int* bsum, int nb) {
    if (threadIdx.x == 0 && blockIdx.x == 0) {
        int run = 0;
        for (int i = 0; i < nb; ++i) { int v = bsum[i]; bsum[i] = run; run += v; }
    }
}

__global__ __launch_bounds__(256)
void k_scan_c(const int* __restrict__ incl, const int* __restrict__ deg,
              const int* __restrict__ bsum, int* __restrict__ rowp, int n) {
    int i = blockIdx.x * 256 + threadIdx.x;
    if (i < n) rowp[i] = incl[i] - deg[i] + bsum[i >> 10];
}

__global__ __launch_bounds__(256)
void k_scatter(const int* __restrict__ src, const int* __restrict__ dst,
               const int* __restrict__ rowp, int* __restrict__ cur,
               int* __restrict__ ss, int E) {
    int i = blockIdx.x * 256 + threadIdx.x;
    if (i < E) {
        int d = dst[i];
        int pos = rowp[d] + atomicAdd(&cur[d], 1);
        ss[pos] = src[i];
    }
}

// ---------------- aggregation (fp16 rows, fp32 accum), fused BN-apply+ReLU ----------------
// 8-deep neighbor unroll: 8 independent 512B gathers in flight per wave (latency hiding).

template<int K, bool AFFINE>
__global__ __launch_bounds__(256)
void k_agg16(const _Float16* __restrict__ h, const int* __restrict__ rowp,
             const int* __restrict__ deg, const int* __restrict__ ss,
             const float* __restrict__ eps, const float* __restrict__ scp,
             const float* __restrict__ shp, _Float16* __restrict__ z, int n) {
    constexpr int TPN = K / 8;
    constexpr int NPB = 256 / TPN;
    int node = blockIdx.x * NPB + threadIdx.x / TPN;
    int lane = threadIdx.x % TPN;
    if (node >= n) return;
    float e1 = 1.0f + eps[0];
    const int c0 = lane * 8;
    float sc[8], sh[8];
    if (AFFINE) {
#pragma unroll
        for (int e = 0; e < 8; ++e) { sc[e] = scp[c0 + e]; sh[e] = shp[c0 + e]; }
    }
    size_t base = (size_t)node * K + c0;
    half8 v = *(const half8*)(h + base);
    float a[8];
#pragma unroll
    for (int e = 0; e < 8; ++e) {
        float f = (float)v[e];
        if (AFFINE) f = fmaxf(f * sc[e] + sh[e], 0.0f);
        a[e] = f * e1;
    }
    int s  = rowp[node];
    int dn = deg[node];
    int j = 0;
    for (; j + 8 <= dn; j += 8) {
        half8 hb[8];
#pragma unroll
        for (int u = 0; u < 8; ++u)
            hb[u] = *(const half8*)(h + (size_t)ss[s + j + u] * K + c0);
#pragma unroll
        for (int e = 0; e < 8; ++e) {
            float t0 = 0.f, t1 = 0.f;
#pragma unroll
            for (int u = 0; u < 4; ++u) {
                float f0 = (float)hb[u][e], f1 = (float)hb[u + 4][e];
                if (AFFINE) {
                    f0 = fmaxf(f0 * sc[e] + sh[e], 0.0f);
                    f1 = fmaxf(f1 * sc[e] + sh[e], 0.0f);
                }
                t0 += f0; t1 += f1;
            }
            a[e] += t0 + t1;
        }
    }
    for (; j + 4 <= dn; j += 4) {
        half8 hb[4];
#pragma unroll
        for (int u = 0; u < 4; ++u)
            hb[u] = *(const half8*)(h + (size_t)ss[s + j + u] * K + c0);
#pragma unroll
        for (int e = 0; e < 8; ++e) {
            float t = 0.f;
#pragma unroll
            for (int u = 0; u < 4; ++u) {
                float f = (float)hb[u][e];
                if (AFFINE) f = fmaxf(f * sc[e] + sh[e], 0.0f);
                t += f;
            }
            a[e] += t;
        }
    }
    for (; j < dn; ++j) {
        int u = ss[s + j];
        half8 hv = *(const half8*)(h + (size_t)u * K + c0);
#pragma unroll
        for (int e = 0; e < 8; ++e) {
            float f = (float)hv[e];
            if (AFFINE) f = fmaxf(f * sc[e] + sh[e], 0.0f);
            a[e] += f;
        }
    }
    half8 o;
#pragma unroll
    for (int e = 0; e < 8; ++e) o[e] = (_Float16)a[e];
    *(half8*)(z + base) = o;
}

// ---------------- fused MLP v3b: persistent, W in regs, 64KB LDS ----------------
// NBLK=256: 1 block/CU (VGPR-bound at ~230 regs anyway), balanced ~3 tiles/block.
// Barriers per tile: alpha (As staged), beta (Ys written), gamma (p2 done).

template<int K, int MID, int MOUT>
__global__ __launch_bounds__(512)
void k_mlp3(const _Float16* __restrict__ A, const _Float16* __restrict__ W1,
            const float* __restrict__ b1, const _Float16* __restrict__ W2,
            const float* __restrict__ b2, _Float16* __restrict__ C,
            float* __restrict__ partial, int n, int ntiles) {
    constexpr int NK1 = K / 16;
    constexpr int NK2 = MID / 16;
    constexpr int MF1 = (MID == 256) ? 2 : 1;
    constexpr int MF2 = (MOUT == 256) ? 2 : 1;
    constexpr int NLD = K / 64;          // uint4 A-loads per thread
    __shared__ char As[64 * 512];        // swizzled: 16B slot l -> l ^ (row&31)
    __shared__ char Ys[64 * 512];        // also hosts per-wave transpose bufs post-gamma
    const int tid  = threadIdx.x;
    const int lane = tid & 63;
    const int wid  = tid >> 6;
    const int lo   = lane & 31;
    const int hi   = lane >> 5;

    const int wc1 = (MID == 256) ? wid : (wid & 3);
    const int wr1 = (MID == 256) ? 0   : (wid >> 2);
    const int colbase1 = wc1 * 32;
    const int wc2 = (MOUT == 256) ? wid : (wid & 3);
    const int wr2 = (MOUT == 256) ? 0   : (wid >> 2);
    const int colbase2 = wc2 * 32;

    // ---- W fragments + biases, once per block (frag-linear: coalesced) ----
    half8 w1f[NK1], w2f[NK2];
#pragma unroll
    for (int ks = 0; ks < NK1; ++ks)
        w1f[ks] = *(const half8*)(W1 + ((size_t)(ks * 2 + hi) * MID + colbase1 + lo) * 8);
#pragma unroll
    for (int ks = 0; ks < NK2; ++ks)
        w2f[ks] = *(const half8*)(W2 + ((size_t)(ks * 2 + hi) * MOUT + colbase2 + lo) * 8);
    const float bb1 = b1[colbase1 + lo];
    const float bb2 = b2[colbase2 + lo];

    const int sr = tid >> 3;         // staging row 0..63
    const int sl = tid & 7;          // staging 16B slot base
    const int g  = lane & 3;         // epilogue col group
    const int rl = lane >> 2;        // epilogue row lane
    char* tb = Ys + wid * 2304;      // [32][72B], valid post-gamma

    float s[8], q[8];
#pragma unroll
    for (int e = 0; e < 8; ++e) { s[e] = 0.f; q[e] = 0.f; }

    int tile = blockIdx.x;
    uint4 ar[NLD];
    if (tile < ntiles) {
        int ga = tile * 64 + sr; if (ga > n - 1) ga = n - 1;
        const char* Ab = (const char*)(A + (size_t)ga * K);
#pragma unroll
        for (int i = 0; i < NLD; ++i) ar[i] = *(const uint4*)(Ab + (sl + i * 8) * 16);
    }

    for (; tile < ntiles; tile += gridDim.x) {
        const int brow = tile * 64;

        // (1) As <- ar  (post-beta of prev iter: As readers done; tb readers done pre-alpha)
#pragma unroll
        for (int i = 0; i < NLD; ++i)
            *(uint4*)(As + sr * 512 + (((sl + i * 8) ^ (sr & 31)) << 4)) = ar[i];
        int nt = tile + gridDim.x;
        if (nt < ntiles) {
            int ga = nt * 64 + sr; if (ga > n - 1) ga = n - 1;
            const char* Ab = (const char*)(A + (size_t)ga * K);
#pragma unroll
            for (int i = 0; i < NLD; ++i) ar[i] = *(const uint4*)(Ab + (sl + i * 8) * 16);
        }
        __syncthreads();   // alpha: As ready; all waves' epilogue (tb in Ys) done

        // ---- phase 1: Y = relu(A @ W1^T + b1) ----
        f32x16 acc1[MF1];
#pragma unroll
        for (int mf = 0; mf < MF1; ++mf)
#pragma unroll
            for (int e = 0; e < 16; ++e) acc1[mf][e] = 0.0f;
#pragma unroll
        for (int ks = 0; ks < NK1; ++ks) {
#pragma unroll
            for (int mf = 0; mf < MF1; ++mf) {
                int r = ((wr1 + mf) << 5) + lo;
                half8 af = *(const half8*)(As + r * 512 + ((ks * 32 + hi * 16) ^ ((r & 31) << 4)));
                acc1[mf] = __builtin_amdgcn_mfma_f32_32x32x16_f16(af, w1f[ks], acc1[mf], 0, 0, 0);
            }
        }
#pragma unroll
        for (int mf = 0; mf < MF1; ++mf) {
            int rb = ((wr1 + mf) << 5) + (hi << 2);
#pragma unroll
            for (int j = 0; j < 16; ++j) {
                int r = rb + (j & 3) + ((j >> 2) << 3);
                float v = fmaxf(acc1[mf][j] + bb1, 0.0f);
                *(_Float16*)(Ys + r * 512 + (((colbase1 + lo) * 2) ^ ((r & 31) << 4))) = (_Float16)v;
            }
        }
        __syncthreads();   // beta: Ys ready; As fully consumed

        // ---- phase 2: C = Y @ W2^T + b2 ----
        f32x16 acc2[MF2];
#pragma unroll
        for (int mf = 0; mf < MF2; ++mf)
#pragma unroll
            for (int e = 0; e < 16; ++e) acc2[mf][e] = 0.0f;
#pragma unroll
        for (int ks = 0; ks < NK2; ++ks) {
#pragma unroll
            for (int mf = 0; mf < MF2; ++mf) {
                int r = ((wr2 + mf) << 5) + lo;
                half8 af = *(const half8*)(Ys + r * 512 + ((ks * 32 + hi * 16) ^ ((r & 31) << 4)));
                acc2[mf] = __builtin_amdgcn_mfma_f32_32x32x16_f16(af, w2f[ks], acc2[mf], 0, 0, 0);
            }
        }
        __syncthreads();   // gamma: all waves done reading Ys; tb region reusable

        // ---- epilogue: per-wave LDS transpose -> coalesced stores + BN accum ----
#pragma unroll
        for (int mf = 0; mf < MF2; ++mf) {
#pragma unroll
            for (int j = 0; j < 16; ++j) {
                int tr = (j & 3) + ((j >> 2) << 3) + (hi << 2);
                *(_Float16*)(tb + tr * 72 + lo * 2) = (_Float16)(acc2[mf][j] + bb2);
            }
            // per-wave DS ops in order: reads below see writes above
#pragma unroll
            for (int it = 0; it < 2; ++it) {
                int lr = it * 16 + rl;
                int grow = brow + ((wr2 + mf) << 5) + lr;
                half8 v = *(const half8*)(tb + lr * 72 + g * 16);
                if (grow < n) {
                    *(half8*)(C + (size_t)grow * MOUT + colbase2 + g * 8) = v;
#pragma unroll
                    for (int e = 0; e < 8; ++e) { float f = (float)v[e]; s[e] += f; q[e] += f * f; }
                }
            }
        }
    }

    // ---- BN partials: one row per (block, row-group), written once ----
#pragma unroll
    for (int e = 0; e < 8; ++e) {
        for (int mk = 4; mk < 64; mk <<= 1) {
            s[e] += __shfl_xor(s[e], mk, 64);
            q[e] += __shfl_xor(q[e], mk, 64);
        }
    }
    if (lane < 4) {
        float* p = partial + ((size_t)blockIdx.x * 2 + wr2) * (2 * MOUT);
#pragma unroll
        for (int e = 0; e < 8; ++e) {
            p[colbase2 + lane * 8 + e]        = s[e];
            p[MOUT + colbase2 + lane * 8 + e] = q[e];
        }
    }
}

// ---------------- BN reduce: strided partial rows -> scale/shift ----------------

template<int M>
__global__ __launch_bounds__(256)
void k_bnred(const float* __restrict__ partial, const float* __restrict__ gamma,
             const float* __restrict__ beta, float* __restrict__ scale,
             float* __restrict__ shift, int n, int count, int step) {
    const int w = threadIdx.x >> 6, lane = threadIdx.x & 63;
    const int c = blockIdx.x * 4 + w;
    float s = 0.f, q = 0.f;
    for (int b = lane; b < count; b += 64) {
        const float* p = partial + (size_t)(b * step) * (2 * M);
        s += p[c];
        q += p[M + c];
    }
#pragma unroll
    for (int mk = 1; mk < 64; mk <<= 1) {
        s += __shfl_xor(s, mk, 64);
        q += __shfl_xor(q, mk, 64);
    }
    if (lane == 0) {
        float invN = 1.0f / (float)n;
        float mean = s * invN;
        float var  = q * invN - mean * mean;
        float sc   = rsqrtf(var + 1e-5f) * gamma[c];
        scale[c] = sc;
        shift[c] = beta[c] - mean * sc;
    }
}

// ---------------- graph readout v2: wide parallel, per-block partials ----------------

__global__ __launch_bounds__(256)
void k_readout2(const _Float16* __restrict__ z, const float* __restrict__ scale,
                const float* __restrict__ shift, const int* __restrict__ gid,
                float* __restrict__ rpart, int* __restrict__ rcnt, int n) {
    __shared__ float ls[NG * 128];
    __shared__ int   lc[NG];
    for (int i = threadIdx.x; i < NG * 128; i += 256) ls[i] = 0.0f;
    if (threadIdx.x < NG) lc[threadIdx.x] = 0;
    __syncthreads();
    const int c16 = threadIdx.x & 15;
    const int ro  = threadIdx.x >> 4;       // 0..15
    const int c0  = c16 * 8;
    float sc[8], sh[8];
#pragma unroll
    for (int e = 0; e < 8; ++e) { sc[e] = scale[c0 + e]; sh[e] = shift[c0 + e]; }
    for (int r = blockIdx.x * 16 + ro; r < n; r += gridDim.x * 16) {
        int g = gid[r];
        half8 v = *(const half8*)(z + (size_t)r * 128 + c0);
#pragma unroll
        for (int e = 0; e < 8; ++e)
            atomicAdd(&ls[g * 128 + c0 + e], (float)v[e] * sc[e] + sh[e]);
        if (c16 == 0) atomicAdd(&lc[g], 1);
    }
    __syncthreads();
    float* p = rpart + (size_t)blockIdx.x * (NG * 128);
    for (int i = threadIdx.x; i < NG * 128; i += 256) p[i] = ls[i];
    if (threadIdx.x < NG) rcnt[blockIdx.x * NG + threadIdx.x] = lc[threadIdx.x];
}

// ---------------- final: one wave per output column ----------------

__global__ __launch_bounds__(256)
void k_final3(const float* __restrict__ rpart, const int* __restrict__ rcnt,
              float* __restrict__ out, int nbr) {
    const int w = threadIdx.x >> 6, lane = threadIdx.x & 63;
    const int i = blockIdx.x * 4 + w;        // column 0..1023
    const int g = i >> 7;
    float s = 0.0f;
    int cnt = 0;
    for (int b = lane; b < nbr; b += 64) {
        s   += rpart[(size_t)b * (NG * 128) + i];
        cnt += rcnt[b * NG + g];
    }
#pragma unroll
    for (int mk = 1; mk < 64; mk <<= 1) {
        s   += __shfl_xor(s, mk, 64);
        cnt += __shfl_xor(cnt, mk, 64);
    }
    if (lane == 0) out[i] = s / fmaxf((float)cnt, 1.0f);
}

// ---------------- host ----------------

extern "C" void kernel_launch(void* const* d_in, const int* in_sizes, int n_in,
                              void* d_out, int out_size, void* d_ws, size_t ws_size,
                              hipStream_t stream) {
    const float* x   = (const float*)d_in[0];
    const int*   src = (const int*)d_in[1];
    const int*   dst = (const int*)d_in[2];
    const int*   gid = (const int*)d_in[3];
    const int n = in_sizes[0] / 128;
    const int E = in_sizes[1];

    auto align = [](size_t o) { return (o + 255) & ~(size_t)255; };
    char* ws = (char*)d_ws;
    size_t off = 0;
    const size_t SZ_H = align((size_t)n * 256 * sizeof(_Float16));
    const size_t SZ_I = align((size_t)n * sizeof(int));
    const int gx = (n + 63) / 64;
    const int NBLK = 256;   // 1 block/CU, ~3 tiles/block (balanced)
    const int RB   = 1024;  // readout blocks

    _Float16* h0 = (_Float16*)(ws + off); off += align((size_t)n * 128 * sizeof(_Float16));
    _Float16* P0 = (_Float16*)(ws + off); off += SZ_H;
    _Float16* P1 = (_Float16*)(ws + off); off += SZ_H;
    int*   deg  = (int*)(ws + off);   off += SZ_I;
    int*   incl = (int*)(ws + off);   off += SZ_I;
    int*   rowp = (int*)(ws + off);   off += SZ_I;
    int*   cur  = (int*)(ws + off);   off += SZ_I;
    int*   bsum = (int*)(ws + off);   off += 256 * sizeof(int);
    int*   ss   = (int*)(ws + off);   off += align((size_t)E * sizeof(int));
    float* partial = (float*)(ws + off); off += align((size_t)(2 * NBLK) * 2 * 256 * sizeof(float));
    float* scale   = (float*)(ws + off); off += align(256 * sizeof(float));
    float* shiftb  = (float*)(ws + off); off += align(256 * sizeof(float));
    float* rpart = (float*)(ws + off); off += align((size_t)RB * NG * 128 * sizeof(float));
    int*   rcnt  = (int*)(ws + off);  off += align((size_t)RB * NG * sizeof(int));
    _Float16* wh[6];
    for (int i = 0; i < 6; ++i) { wh[i] = (_Float16*)(ws + off); off += align(65536 * sizeof(_Float16)); }

    // ---- casts ----
    k_cast16<<<(n * 128 / 8 + 255) / 256, 256, 0, stream>>>(x, h0, n * 128 / 8);
    k_castw<<<136, 256, 0, stream>>>(
        (const float*)d_in[4], (const float*)d_in[6],
        (const float*)d_in[11], (const float*)d_in[13],
        (const float*)d_in[18], (const float*)d_in[20],
        wh[0], wh[1], wh[2], wh[3], wh[4], wh[5]);

    // ---- CSR build (dst-keyed) ----
    hipMemsetAsync(deg, 0, (size_t)n * sizeof(int), stream);
    k_deg<<<(E + 255) / 256, 256, 0, stream>>>(dst, deg, E);
    int nb = (n + 1023) / 1024;
    k_scan_a<<<nb, 1024, 0, stream>>>(deg, incl, bsum, n);
    k_scan_b<<<1, 1, 0, stream>>>(bsum, nb);
    k_scan_c<<<(n + 255) / 256, 256, 0, stream>>>(incl, deg, bsum, rowp, n);
    hipMemsetAsync(cur, 0, (size_t)n * sizeof(int), stream);
    k_scatter<<<(E + 255) / 256, 256, 0, stream>>>(src, dst, rowp, cur, ss, E);

    // ---- layers ----
    for (int L = 0; L < 3; ++L) {
        const int base = 4 + 7 * L;
        const float* b1    = (const float*)d_in[base + 1];
        const float* b2    = (const float*)d_in[base + 3];
        const float* eps   = (const float*)d_in[base + 4];
        const float* gamma = (const float*)d_in[base + 5];
        const float* beta  = (const float*)d_in[base + 6];

        if (L == 0) {
            k_agg16<128, false><<<(n + 15) / 16, 256, 0, stream>>>(
                h0, rowp, deg, ss, eps, nullptr, nullptr, P1, n);
            k_mlp3<128, 256, 256><<<NBLK, 512, 0, stream>>>(P1, wh[0], b1, wh[1], b2, P0, partial, n, gx);
            k_bnred<256><<<64, 256, 0, stream>>>(partial, gamma, beta, scale, shiftb, n, NBLK, 2);
        } else if (L == 1) {
            k_agg16<256, true><<<(n + 7) / 8, 256, 0, stream>>>(
                P0, rowp, deg, ss, eps, scale, shiftb, P1, n);
            k_mlp3<256, 256, 256><<<NBLK, 512, 0, stream>>>(P1, wh[2], b1, wh[3], b2, P0, partial, n, gx);
            k_bnred<256><<<64, 256, 0, stream>>>(partial, gamma, beta, scale, shiftb, n, NBLK, 2);
        } else {
            k_agg16<256, true><<<(n + 7) / 8, 256, 0, stream>>>(
                P0, rowp, deg, ss, eps, scale, shiftb, P1, n);
            k_mlp3<256, 128, 128><<<NBLK, 512, 0, stream>>>(P1, wh[4], b1, wh[5], b2, P0, partial, n, gx);
            k_bnred<128><<<32, 256, 0, stream>>>(partial, gamma, beta, scale, shiftb, n, 2 * NBLK, 1);
        }
    }

    // ---- readout (applies layer-2 BN affine) ----
    k_readout2<<<RB, 256, 0, stream>>>(P0, scale, shiftb, gid, rpart, rcnt, n);
    k_final3<<<256, 256, 0, stream>>>(rpart, rcnt, (float*)d_out, RB);
}